// Round 1
// baseline (888.955 us; speedup 1.0000x reference)
//
#include <hip/hip_runtime.h>

#define NN 100000
#define NE 1600000

// ---------------- CSR build ----------------

__global__ void count_k(const int* __restrict__ dst, int* __restrict__ cnt) {
    int e = blockIdx.x * 256 + threadIdx.x;
    if (e < NE) atomicAdd(&cnt[dst[e]], 1);
}

__global__ void scan_partial_k(const int* __restrict__ cnt, int* __restrict__ part) {
    __shared__ int sh[256];
    int t = threadIdx.x;
    int base = blockIdx.x * 1024 + t * 4;
    int s = 0;
#pragma unroll
    for (int j = 0; j < 4; ++j) { int i = base + j; if (i < NN) s += cnt[i]; }
    sh[t] = s;
    __syncthreads();
    for (int d = 128; d > 0; d >>= 1) { if (t < d) sh[t] += sh[t + d]; __syncthreads(); }
    if (t == 0) part[blockIdx.x] = sh[0];
}

__global__ void scan_top_k(int* part, int nb) {
    if (threadIdx.x == 0 && blockIdx.x == 0) {
        int run = 0;
        for (int i = 0; i < nb; ++i) { int v = part[i]; part[i] = run; run += v; }
    }
}

__global__ void scan_offsets_k(const int* __restrict__ cnt, const int* __restrict__ part,
                               int* __restrict__ offs, int* __restrict__ cur) {
    __shared__ int sh[256];
    int t = threadIdx.x;
    int base = blockIdx.x * 1024 + t * 4;
    int v[4]; int s = 0;
#pragma unroll
    for (int j = 0; j < 4; ++j) { int i = base + j; v[j] = (i < NN) ? cnt[i] : 0; s += v[j]; }
    sh[t] = s;
    __syncthreads();
    if (t == 0) {
        int run = 0;
        for (int i = 0; i < 256; ++i) { int tmp = sh[i]; sh[i] = run; run += tmp; }
    }
    __syncthreads();
    int excl = part[blockIdx.x] + sh[t];
#pragma unroll
    for (int j = 0; j < 4; ++j) {
        int i = base + j;
        if (i < NN) { offs[i] = excl; cur[i] = excl; }
        excl += v[j];
    }
    if (blockIdx.x == 0 && t == 0) offs[NN] = NE;
}

__global__ void dinv_k(const int* __restrict__ cnt, float* __restrict__ dinv) {
    int i = blockIdx.x * 256 + threadIdx.x;
    if (i < NN) dinv[i] = rsqrtf((float)(cnt[i] + 1));
}

__global__ void fill_k(const int* __restrict__ src, const int* __restrict__ dst,
                       int* __restrict__ cur, int* __restrict__ csrc) {
    int e = blockIdx.x * 256 + threadIdx.x;
    if (e < NE) {
        int d = dst[e];
        int p = atomicAdd(&cur[d], 1);
        csrc[p] = src[e];
    }
}

// ---------------- dense GEMM: H[N,128] = X[N,128] @ W[128,128] ----------------

__global__ __launch_bounds__(256) void gemm128_k(const float* __restrict__ X,
                                                 const float* __restrict__ W,
                                                 float* __restrict__ H) {
    __shared__ float xs[64][132];   // +4 pad: breaks power-of-2 bank stride
    int t = threadIdx.x;
    int row0 = blockIdx.x * 64;
    for (int i = t; i < 64 * 32; i += 256) {
        int r = i >> 5, c4 = i & 31;
        int row = row0 + r;
        float4 v = make_float4(0.f, 0.f, 0.f, 0.f);
        if (row < NN) v = ((const float4*)(X + (size_t)row * 128))[c4];
        *(float4*)&xs[r][c4 * 4] = v;
    }
    __syncthreads();
    int tx = t & 15, ty = t >> 4;      // 16 col-groups x 16 row-groups
    float acc[4][8];
#pragma unroll
    for (int r = 0; r < 4; ++r)
#pragma unroll
        for (int j = 0; j < 8; ++j) acc[r][j] = 0.f;

    for (int k = 0; k < 128; ++k) {
        float4 w0 = *(const float4*)(W + k * 128 + tx * 8);
        float4 w1 = *(const float4*)(W + k * 128 + tx * 8 + 4);
        float xv[4];
#pragma unroll
        for (int r = 0; r < 4; ++r) xv[r] = xs[ty * 4 + r][k];
#pragma unroll
        for (int r = 0; r < 4; ++r) {
            acc[r][0] = fmaf(xv[r], w0.x, acc[r][0]);
            acc[r][1] = fmaf(xv[r], w0.y, acc[r][1]);
            acc[r][2] = fmaf(xv[r], w0.z, acc[r][2]);
            acc[r][3] = fmaf(xv[r], w0.w, acc[r][3]);
            acc[r][4] = fmaf(xv[r], w1.x, acc[r][4]);
            acc[r][5] = fmaf(xv[r], w1.y, acc[r][5]);
            acc[r][6] = fmaf(xv[r], w1.z, acc[r][6]);
            acc[r][7] = fmaf(xv[r], w1.w, acc[r][7]);
        }
    }
#pragma unroll
    for (int r = 0; r < 4; ++r) {
        int row = row0 + ty * 4 + r;
        if (row < NN) {
            float4* Hp = (float4*)(H + (size_t)row * 128 + tx * 8);
            Hp[0] = make_float4(acc[r][0], acc[r][1], acc[r][2], acc[r][3]);
            Hp[1] = make_float4(acc[r][4], acc[r][5], acc[r][6], acc[r][7]);
        }
    }
}

// ---------------- edge aggregation (atomic-free, CSR by dst) ----------------
// out[i,c] = dinv[i] * ( sum_e dinv[src_e]*h[src_e,c] + dinv[i]*h[i,c] ) + bias[c]

__global__ __launch_bounds__(128) void aggregate_k(const float* __restrict__ h,
                                                   const int* __restrict__ offs,
                                                   const int* __restrict__ csrc,
                                                   const float* __restrict__ dinv,
                                                   const float* __restrict__ bias,
                                                   float* __restrict__ out) {
    int node = blockIdx.x;
    int c = threadIdx.x;
    int beg = offs[node], end = offs[node + 1];
    float di = dinv[node];
    float acc = di * h[(size_t)node * 128 + c];   // self-loop (x dinv once more below)
    int e = beg;
    int s = (e < end) ? csrc[e] : 0;
    for (; e < end; ++e) {
        int snext = (e + 1 < end) ? csrc[e + 1] : 0;
        acc = fmaf(dinv[s], h[(size_t)s * 128 + c], acc);
        s = snext;
    }
    out[(size_t)node * 128 + c] = fmaf(di, acc, bias[c]);
}

// ---------------- GraphNorm ----------------

__global__ __launch_bounds__(256) void colstats_k(const float* __restrict__ A,
                                                  float* __restrict__ stats) {
    __shared__ float sh[512];
    int t = threadIdx.x;
    int c = t & 127;
    float s = 0.f, q = 0.f;
    for (int r = blockIdx.x * 2 + (t >> 7); r < NN; r += gridDim.x * 2) {
        float v = A[(size_t)r * 128 + c];
        s += v; q = fmaf(v, v, q);
    }
    sh[t] = s; sh[256 + t] = q;
    __syncthreads();
    if (t < 128) {
        atomicAdd(&stats[c], sh[t] + sh[t + 128]);
        atomicAdd(&stats[128 + c], sh[256 + t] + sh[256 + t + 128]);
    }
}

__global__ void gnparams_k(const float* __restrict__ stats, const float* __restrict__ w,
                           const float* __restrict__ b, const float* __restrict__ a,
                           float* __restrict__ par) {
    int c = threadIdx.x;
    if (c < 128) {
        float m = stats[c] * (1.0f / NN);
        float ex2 = stats[128 + c] * (1.0f / NN);
        float ac = a[c];
        // var of (x - a*m): E[x^2] - 2*a*m*E[x] + a^2*m^2, with E[x] = m
        float var = ex2 - 2.0f * ac * m * m + ac * ac * m * m;
        float sc = w[c] * rsqrtf(var + 1e-5f);
        par[c] = sc;                      // scale
        par[128 + c] = b[c] - sc * ac * m; // shift
    }
}

__global__ void gnrelu_k(float* __restrict__ A, const float* __restrict__ par) {
    size_t stride = (size_t)gridDim.x * blockDim.x;
    for (size_t i = (size_t)blockIdx.x * blockDim.x + threadIdx.x; i < (size_t)NN * 32; i += stride) {
        float4 v = ((float4*)A)[i];
        int c4 = ((int)(i & 31)) * 4;
        v.x = fmaxf(0.f, fmaf(par[c4 + 0], v.x, par[128 + c4 + 0]));
        v.y = fmaxf(0.f, fmaf(par[c4 + 1], v.y, par[128 + c4 + 1]));
        v.z = fmaxf(0.f, fmaf(par[c4 + 2], v.z, par[128 + c4 + 2]));
        v.w = fmaxf(0.f, fmaf(par[c4 + 3], v.w, par[128 + c4 + 3]));
        ((float4*)A)[i] = v;
    }
}

// ---------------- head: out = [x, x2] @ Wh + bh ----------------

__global__ __launch_bounds__(256) void final_k(const float* __restrict__ x,
                                               const float* __restrict__ x2,
                                               const float* __restrict__ Wh,
                                               const float* __restrict__ bh,
                                               float* __restrict__ out) {
    __shared__ float wl[256][16];
    int t = threadIdx.x;
    for (int i = t; i < 256 * 16; i += 256) wl[i >> 4][i & 15] = Wh[i];
    __syncthreads();
    int row = blockIdx.x * 16 + (t >> 4);
    int o = t & 15;
    if (row >= NN) return;
    const float4* xp = (const float4*)(x + (size_t)row * 128);
    const float4* x2p = (const float4*)(x2 + (size_t)row * 128);
    float acc = bh[o];
#pragma unroll
    for (int k4 = 0; k4 < 32; ++k4) {
        float4 v = xp[k4];
        acc = fmaf(v.x, wl[k4 * 4 + 0][o], acc);
        acc = fmaf(v.y, wl[k4 * 4 + 1][o], acc);
        acc = fmaf(v.z, wl[k4 * 4 + 2][o], acc);
        acc = fmaf(v.w, wl[k4 * 4 + 3][o], acc);
    }
#pragma unroll
    for (int k4 = 0; k4 < 32; ++k4) {
        float4 v = x2p[k4];
        acc = fmaf(v.x, wl[128 + k4 * 4 + 0][o], acc);
        acc = fmaf(v.y, wl[128 + k4 * 4 + 1][o], acc);
        acc = fmaf(v.z, wl[128 + k4 * 4 + 2][o], acc);
        acc = fmaf(v.w, wl[128 + k4 * 4 + 3][o], acc);
    }
    out[(size_t)row * 16 + o] = acc;
}

// ---------------- launch ----------------

extern "C" void kernel_launch(void* const* d_in, const int* in_sizes, int n_in,
                              void* d_out, int out_size, void* d_ws, size_t ws_size,
                              hipStream_t stream) {
    const float* x   = (const float*)d_in[0];
    const int*   ei  = (const int*)d_in[1];
    const float* W1  = (const float*)d_in[2];
    const float* b1  = (const float*)d_in[3];
    const float* g1w = (const float*)d_in[4];
    const float* g1b = (const float*)d_in[5];
    const float* g1a = (const float*)d_in[6];
    const float* W2  = (const float*)d_in[7];
    const float* b2  = (const float*)d_in[8];
    const float* g2w = (const float*)d_in[9];
    const float* g2b = (const float*)d_in[10];
    const float* g2a = (const float*)d_in[11];
    const float* Wh  = (const float*)d_in[12];
    const float* bh  = (const float*)d_in[13];
    const int* srcp = ei;        // edge_index row 0
    const int* dstp = ei + NE;   // edge_index row 1
    float* out = (float*)d_out;

    char* p = (char*)d_ws;
    auto take = [&](size_t bytes) { char* r = p; p += (bytes + 255) & ~(size_t)255; return r; };
    int*   cnt    = (int*)take((size_t)NN * 4);
    int*   offs   = (int*)take((size_t)(NN + 1) * 4);
    int*   cur    = (int*)take((size_t)NN * 4);
    int*   csrc   = (int*)take((size_t)NE * 4);
    float* dinv   = (float*)take((size_t)NN * 4);
    int*   part   = (int*)take(128 * 4);
    float* stats1 = (float*)take(256 * 4);
    float* stats2 = (float*)take(256 * 4);
    float* par1   = (float*)take(256 * 4);
    float* par2   = (float*)take(256 * 4);
    float* bufH   = (float*)take((size_t)NN * 128 * 4);
    float* bufA   = (float*)take((size_t)NN * 128 * 4);

    hipMemsetAsync(cnt, 0, (size_t)NN * 4, stream);
    hipMemsetAsync(stats1, 0, 256 * 4, stream);
    hipMemsetAsync(stats2, 0, 256 * 4, stream);

    count_k<<<(NE + 255) / 256, 256, 0, stream>>>(dstp, cnt);
    scan_partial_k<<<98, 256, 0, stream>>>(cnt, part);
    scan_top_k<<<1, 1, 0, stream>>>(part, 98);
    scan_offsets_k<<<98, 256, 0, stream>>>(cnt, part, offs, cur);
    dinv_k<<<(NN + 255) / 256, 256, 0, stream>>>(cnt, dinv);
    fill_k<<<(NE + 255) / 256, 256, 0, stream>>>(srcp, dstp, cur, csrc);

    // layer 1
    gemm128_k<<<(NN + 63) / 64, 256, 0, stream>>>(x, W1, bufH);
    aggregate_k<<<NN, 128, 0, stream>>>(bufH, offs, csrc, dinv, b1, bufA);
    colstats_k<<<512, 256, 0, stream>>>(bufA, stats1);
    gnparams_k<<<1, 128, 0, stream>>>(stats1, g1w, g1b, g1a, par1);
    gnrelu_k<<<2048, 256, 0, stream>>>(bufA, par1);   // bufA = x1

    // layer 2
    gemm128_k<<<(NN + 63) / 64, 256, 0, stream>>>(bufA, W2, bufH);
    aggregate_k<<<NN, 128, 0, stream>>>(bufH, offs, csrc, dinv, b2, bufA);
    colstats_k<<<512, 256, 0, stream>>>(bufA, stats2);
    gnparams_k<<<1, 128, 0, stream>>>(stats2, g2w, g2b, g2a, par2);
    gnrelu_k<<<2048, 256, 0, stream>>>(bufA, par2);   // bufA = x2

    // head
    final_k<<<(NN + 15) / 16, 256, 0, stream>>>(x, bufA, Wh, bh, out);
}

// Round 2
// 807.971 us; speedup vs baseline: 1.1002x; 1.1002x over previous
//
#include <hip/hip_runtime.h>

#define NN 100000
#define NE 1600000

typedef unsigned int uint32;
typedef unsigned short ushort16;

__device__ inline unsigned short f2bf(float f) {
    uint32 u = __float_as_uint(f);
    u += 0x7FFFu + ((u >> 16) & 1u);      // round to nearest even
    return (unsigned short)(u >> 16);
}
__device__ inline float bflo(uint32 v) { return __uint_as_float(v << 16); }
__device__ inline float bfhi(uint32 v) { return __uint_as_float(v & 0xFFFF0000u); }

// ---------------- CSR build ----------------

__global__ void count_k(const int* __restrict__ dst, int* __restrict__ cnt) {
    int e = blockIdx.x * 256 + threadIdx.x;
    if (e < NE) atomicAdd(&cnt[dst[e]], 1);
}

__global__ void scan_partial_k(const int* __restrict__ cnt, int* __restrict__ part) {
    __shared__ int sh[256];
    int t = threadIdx.x;
    int base = blockIdx.x * 1024 + t * 4;
    int s = 0;
#pragma unroll
    for (int j = 0; j < 4; ++j) { int i = base + j; if (i < NN) s += cnt[i]; }
    sh[t] = s;
    __syncthreads();
    for (int d = 128; d > 0; d >>= 1) { if (t < d) sh[t] += sh[t + d]; __syncthreads(); }
    if (t == 0) part[blockIdx.x] = sh[0];
}

__global__ void scan_top_k(int* part, int nb) {
    if (threadIdx.x == 0 && blockIdx.x == 0) {
        int run = 0;
        for (int i = 0; i < nb; ++i) { int v = part[i]; part[i] = run; run += v; }
    }
}

__global__ void scan_offsets_k(const int* __restrict__ cnt, const int* __restrict__ part,
                               int* __restrict__ offs, int* __restrict__ cur) {
    __shared__ int sh[256];
    int t = threadIdx.x;
    int base = blockIdx.x * 1024 + t * 4;
    int v[4]; int s = 0;
#pragma unroll
    for (int j = 0; j < 4; ++j) { int i = base + j; v[j] = (i < NN) ? cnt[i] : 0; s += v[j]; }
    sh[t] = s;
    __syncthreads();
    if (t == 0) {
        int run = 0;
        for (int i = 0; i < 256; ++i) { int tmp = sh[i]; sh[i] = run; run += tmp; }
    }
    __syncthreads();
    int excl = part[blockIdx.x] + sh[t];
#pragma unroll
    for (int j = 0; j < 4; ++j) {
        int i = base + j;
        if (i < NN) { offs[i] = excl; cur[i] = excl; }
        excl += v[j];
    }
    if (blockIdx.x == 0 && t == 0) offs[NN] = NE;
}

__global__ void dinv_k(const int* __restrict__ cnt, float* __restrict__ dinv) {
    int i = blockIdx.x * 256 + threadIdx.x;
    if (i < NN) dinv[i] = rsqrtf((float)(cnt[i] + 1));
}

__global__ void fill_k(const int* __restrict__ src, const int* __restrict__ dst,
                       int* __restrict__ cur, int* __restrict__ csrc) {
    int e = blockIdx.x * 256 + threadIdx.x;
    if (e < NE) {
        int d = dst[e];
        int p = atomicAdd(&cur[d], 1);
        csrc[p] = src[e];
    }
}

// ---------------- dense GEMM: H[N,128](bf16) = act(X[N,128]) @ W[128,128] ----
// AFF=1: apply per-channel relu(sc*x+sh) (fused GraphNorm+ReLU) while staging X.

template <int AFF>
__global__ __launch_bounds__(256) void gemm128_k(const float* __restrict__ X,
                                                 const float* __restrict__ W,
                                                 const float* __restrict__ par,
                                                 unsigned short* __restrict__ H) {
    __shared__ float xs[64][132];   // +4 pad: breaks power-of-2 bank stride
    int t = threadIdx.x;
    int row0 = blockIdx.x * 64;
    for (int i = t; i < 64 * 32; i += 256) {
        int r = i >> 5, c4 = i & 31;
        int row = row0 + r;
        float4 v = make_float4(0.f, 0.f, 0.f, 0.f);
        if (row < NN) v = ((const float4*)(X + (size_t)row * 128))[c4];
        if (AFF) {
            int c = c4 * 4;
            v.x = fmaxf(0.f, fmaf(par[c + 0], v.x, par[128 + c + 0]));
            v.y = fmaxf(0.f, fmaf(par[c + 1], v.y, par[128 + c + 1]));
            v.z = fmaxf(0.f, fmaf(par[c + 2], v.z, par[128 + c + 2]));
            v.w = fmaxf(0.f, fmaf(par[c + 3], v.w, par[128 + c + 3]));
        }
        *(float4*)&xs[r][c4 * 4] = v;
    }
    __syncthreads();
    int tx = t & 15, ty = t >> 4;      // 16 col-groups x 16 row-groups
    float acc[4][8];
#pragma unroll
    for (int r = 0; r < 4; ++r)
#pragma unroll
        for (int j = 0; j < 8; ++j) acc[r][j] = 0.f;

    for (int k = 0; k < 128; ++k) {
        float4 w0 = *(const float4*)(W + k * 128 + tx * 8);
        float4 w1 = *(const float4*)(W + k * 128 + tx * 8 + 4);
        float xv[4];
#pragma unroll
        for (int r = 0; r < 4; ++r) xv[r] = xs[ty * 4 + r][k];
#pragma unroll
        for (int r = 0; r < 4; ++r) {
            acc[r][0] = fmaf(xv[r], w0.x, acc[r][0]);
            acc[r][1] = fmaf(xv[r], w0.y, acc[r][1]);
            acc[r][2] = fmaf(xv[r], w0.z, acc[r][2]);
            acc[r][3] = fmaf(xv[r], w0.w, acc[r][3]);
            acc[r][4] = fmaf(xv[r], w1.x, acc[r][4]);
            acc[r][5] = fmaf(xv[r], w1.y, acc[r][5]);
            acc[r][6] = fmaf(xv[r], w1.z, acc[r][6]);
            acc[r][7] = fmaf(xv[r], w1.w, acc[r][7]);
        }
    }
#pragma unroll
    for (int r = 0; r < 4; ++r) {
        int row = row0 + ty * 4 + r;
        if (row < NN) {
            uint4 o;
            o.x = (uint32)f2bf(acc[r][0]) | ((uint32)f2bf(acc[r][1]) << 16);
            o.y = (uint32)f2bf(acc[r][2]) | ((uint32)f2bf(acc[r][3]) << 16);
            o.z = (uint32)f2bf(acc[r][4]) | ((uint32)f2bf(acc[r][5]) << 16);
            o.w = (uint32)f2bf(acc[r][6]) | ((uint32)f2bf(acc[r][7]) << 16);
            ((uint4*)(H + (size_t)row * 128))[tx] = o;
        }
    }
}

// ---------------- edge aggregation (atomic-free, CSR by dst, bf16 gather) ----
// out[i,c] = dinv[i]*( sum_e dinv[src]*h[src,c] + dinv[i]*h[i,c] ) + bias[c]
// One wave per node; lane owns channels {2*lane, 2*lane+1} via one uint load.

__global__ __launch_bounds__(256) void aggregate_k(const unsigned short* __restrict__ h,
                                                   const int* __restrict__ offs,
                                                   const int* __restrict__ csrc,
                                                   const float* __restrict__ dinv,
                                                   const float* __restrict__ bias,
                                                   float* __restrict__ out) {
    int t = threadIdx.x;
    int node = blockIdx.x * 4 + (t >> 6);
    if (node >= NN) return;
    int lane = t & 63;
    const uint32* hv = (const uint32*)h;   // row stride = 64 uints
    int beg = offs[node], end = offs[node + 1];
    float di = dinv[node];
    uint32 sv = hv[(size_t)node * 64 + lane];
    float a0 = di * bflo(sv);
    float a1 = di * bfhi(sv);
    int s = (beg < end) ? csrc[beg] : 0;
    for (int e = beg; e < end; ++e) {
        int snext = (e + 1 < end) ? csrc[e + 1] : 0;
        float ds = dinv[s];
        uint32 v = hv[(size_t)s * 64 + lane];
        a0 = fmaf(ds, bflo(v), a0);
        a1 = fmaf(ds, bfhi(v), a1);
        s = snext;
    }
    float2 bb = ((const float2*)bias)[lane];
    float2 o;
    o.x = fmaf(di, a0, bb.x);
    o.y = fmaf(di, a1, bb.y);
    ((float2*)out)[(size_t)node * 64 + lane] = o;
}

// ---------------- GraphNorm stats ----------------

__global__ __launch_bounds__(256) void colstats_k(const float* __restrict__ A,
                                                  float* __restrict__ stats) {
    __shared__ float sh[512];
    int t = threadIdx.x;
    int c = t & 127;
    float s = 0.f, q = 0.f;
    for (int r = blockIdx.x * 2 + (t >> 7); r < NN; r += gridDim.x * 2) {
        float v = A[(size_t)r * 128 + c];
        s += v; q = fmaf(v, v, q);
    }
    sh[t] = s; sh[256 + t] = q;
    __syncthreads();
    if (t < 128) {
        atomicAdd(&stats[c], sh[t] + sh[t + 128]);
        atomicAdd(&stats[128 + c], sh[256 + t] + sh[256 + t + 128]);
    }
}

__global__ void gnparams_k(const float* __restrict__ stats, const float* __restrict__ w,
                           const float* __restrict__ b, const float* __restrict__ a,
                           float* __restrict__ par) {
    int c = threadIdx.x;
    if (c < 128) {
        float m = stats[c] * (1.0f / NN);
        float ex2 = stats[128 + c] * (1.0f / NN);
        float ac = a[c];
        // var of (x - a*m): E[x^2] - 2*a*m^2 + a^2*m^2
        float var = ex2 - 2.0f * ac * m * m + ac * ac * m * m;
        float sc = w[c] * rsqrtf(var + 1e-5f);
        par[c] = sc;                       // scale
        par[128 + c] = b[c] - sc * ac * m; // shift
    }
}

// ---------------- head: out = [x, relu(gn2(x2))] @ Wh + bh ----------------

__global__ __launch_bounds__(256) void final_k(const float* __restrict__ x,
                                               const float* __restrict__ x2,
                                               const float* __restrict__ par,
                                               const float* __restrict__ Wh,
                                               const float* __restrict__ bh,
                                               float* __restrict__ out) {
    __shared__ float wl[256][16];
    int t = threadIdx.x;
    for (int i = t; i < 256 * 16; i += 256) wl[i >> 4][i & 15] = Wh[i];
    __syncthreads();
    int row = blockIdx.x * 16 + (t >> 4);
    int o = t & 15;
    if (row >= NN) return;
    const float4* xp = (const float4*)(x + (size_t)row * 128);
    const float4* x2p = (const float4*)(x2 + (size_t)row * 128);
    float acc = bh[o];
#pragma unroll
    for (int k4 = 0; k4 < 32; ++k4) {
        float4 v = xp[k4];
        acc = fmaf(v.x, wl[k4 * 4 + 0][o], acc);
        acc = fmaf(v.y, wl[k4 * 4 + 1][o], acc);
        acc = fmaf(v.z, wl[k4 * 4 + 2][o], acc);
        acc = fmaf(v.w, wl[k4 * 4 + 3][o], acc);
    }
#pragma unroll
    for (int k4 = 0; k4 < 32; ++k4) {
        float4 v = x2p[k4];
        int c = k4 * 4;
        v.x = fmaxf(0.f, fmaf(par[c + 0], v.x, par[128 + c + 0]));
        v.y = fmaxf(0.f, fmaf(par[c + 1], v.y, par[128 + c + 1]));
        v.z = fmaxf(0.f, fmaf(par[c + 2], v.z, par[128 + c + 2]));
        v.w = fmaxf(0.f, fmaf(par[c + 3], v.w, par[128 + c + 3]));
        acc = fmaf(v.x, wl[128 + c + 0][o], acc);
        acc = fmaf(v.y, wl[128 + c + 1][o], acc);
        acc = fmaf(v.z, wl[128 + c + 2][o], acc);
        acc = fmaf(v.w, wl[128 + c + 3][o], acc);
    }
    out[(size_t)row * 16 + o] = acc;
}

// ---------------- launch ----------------

extern "C" void kernel_launch(void* const* d_in, const int* in_sizes, int n_in,
                              void* d_out, int out_size, void* d_ws, size_t ws_size,
                              hipStream_t stream) {
    const float* x   = (const float*)d_in[0];
    const int*   ei  = (const int*)d_in[1];
    const float* W1  = (const float*)d_in[2];
    const float* b1  = (const float*)d_in[3];
    const float* g1w = (const float*)d_in[4];
    const float* g1b = (const float*)d_in[5];
    const float* g1a = (const float*)d_in[6];
    const float* W2  = (const float*)d_in[7];
    const float* b2  = (const float*)d_in[8];
    const float* g2w = (const float*)d_in[9];
    const float* g2b = (const float*)d_in[10];
    const float* g2a = (const float*)d_in[11];
    const float* Wh  = (const float*)d_in[12];
    const float* bh  = (const float*)d_in[13];
    const int* srcp = ei;        // edge_index row 0
    const int* dstp = ei + NE;   // edge_index row 1
    float* out = (float*)d_out;

    char* p = (char*)d_ws;
    auto take = [&](size_t bytes) { char* r = p; p += (bytes + 255) & ~(size_t)255; return r; };
    int*   cnt    = (int*)take((size_t)NN * 4);
    int*   offs   = (int*)take((size_t)(NN + 1) * 4);
    int*   cur    = (int*)take((size_t)NN * 4);
    int*   csrc   = (int*)take((size_t)NE * 4);
    float* dinv   = (float*)take((size_t)NN * 4);
    int*   part   = (int*)take(128 * 4);
    float* stats1 = (float*)take(256 * 4);
    float* stats2 = (float*)take(256 * 4);
    float* par1   = (float*)take(256 * 4);
    float* par2   = (float*)take(256 * 4);
    unsigned short* bufH = (unsigned short*)take((size_t)NN * 128 * 2);  // bf16
    float* bufA   = (float*)take((size_t)NN * 128 * 4);

    hipMemsetAsync(cnt, 0, (size_t)NN * 4, stream);
    hipMemsetAsync(stats1, 0, 256 * 4, stream);
    hipMemsetAsync(stats2, 0, 256 * 4, stream);

    count_k<<<(NE + 255) / 256, 256, 0, stream>>>(dstp, cnt);
    scan_partial_k<<<98, 256, 0, stream>>>(cnt, part);
    scan_top_k<<<1, 1, 0, stream>>>(part, 98);
    scan_offsets_k<<<98, 256, 0, stream>>>(cnt, part, offs, cur);
    dinv_k<<<(NN + 255) / 256, 256, 0, stream>>>(cnt, dinv);
    fill_k<<<(NE + 255) / 256, 256, 0, stream>>>(srcp, dstp, cur, csrc);

    // layer 1: h1 = x @ W1 (bf16), agg -> bufA, stats -> par1
    gemm128_k<0><<<(NN + 63) / 64, 256, 0, stream>>>(x, W1, nullptr, bufH);
    aggregate_k<<<(NN + 3) / 4, 256, 0, stream>>>(bufH, offs, csrc, dinv, b1, bufA);
    colstats_k<<<512, 256, 0, stream>>>(bufA, stats1);
    gnparams_k<<<1, 128, 0, stream>>>(stats1, g1w, g1b, g1a, par1);

    // layer 2: h2 = relu(gn1(bufA)) @ W2 (fused affine on load), agg, stats
    gemm128_k<1><<<(NN + 63) / 64, 256, 0, stream>>>(bufA, W2, par1, bufH);
    aggregate_k<<<(NN + 3) / 4, 256, 0, stream>>>(bufH, offs, csrc, dinv, b2, bufA);
    colstats_k<<<512, 256, 0, stream>>>(bufA, stats2);
    gnparams_k<<<1, 128, 0, stream>>>(stats2, g2w, g2b, g2a, par2);

    // head: out = [x, relu(gn2(bufA))] @ Wh + bh (gn2 fused on load)
    final_k<<<(NN + 15) / 16, 256, 0, stream>>>(x, bufA, par2, Wh, bh, out);
}